// Round 1
// baseline (1649.024 us; speedup 1.0000x reference)
//
#include <hip/hip_runtime.h>
#include <stdint.h>

#define B_TOTAL 1024
#define T_STEPS 128
#define F_DIM   64
#define H_DIM   256
#define K_DIM   320   // F_DIM + H_DIM
#define NT_TOTAL 64   // 1024 cols / 16
#define KT_TOTAL 10   // 320 / 32
#define BROWS   16
#define APAD    328   // 320 + 8 pad (bank stride 4 -> conflict-free-ish)

typedef float f32x4 __attribute__((ext_vector_type(4)));
typedef short bf16x8 __attribute__((ext_vector_type(8)));

__device__ __forceinline__ unsigned short f2bf(float f) {
  unsigned int u = __float_as_uint(f);
  u += 0x7fffu + ((u >> 16) & 1u);
  return (unsigned short)(u >> 16);
}

__device__ __forceinline__ float sigmoid_f(float x) {
  return 1.0f / (1.0f + __expf(-x));
}

// Pack kernel weights (320x1024 fp32, row-major) into bf16 MFMA-B-fragment order:
// Wp[((ntile*KT + kt)*64 + lane)*8 + j] = W[kt*32 + 8*(lane>>4) + j][ntile*16 + (lane&15)]
__global__ __launch_bounds__(64) void pack_w_kernel(const float* __restrict__ W,
                                                    unsigned short* __restrict__ Wp) {
  const int bid = blockIdx.x;            // = ntile*KT_TOTAL + kt
  const int nt  = bid / KT_TOTAL;
  const int kt  = bid % KT_TOTAL;
  const int l   = threadIdx.x;
  const int col = nt * 16 + (l & 15);
  const int k0  = kt * 32 + (l >> 4) * 8;
  unsigned short* dst = Wp + ((size_t)bid * 64 + l) * 8;
  #pragma unroll
  for (int j = 0; j < 8; ++j)
    dst[j] = f2bf(W[(size_t)(k0 + j) * 1024 + col]);
}

__global__ __launch_bounds__(512) void qlstm_kernel(
    const float* __restrict__ history, const float* __restrict__ head,
    const float* __restrict__ bias,
    const float* __restrict__ w_i, const float* __restrict__ w_f, const float* __restrict__ w_o,
    const unsigned short* __restrict__ Wp,
    const float* __restrict__ fc3_w, const float* __restrict__ fc3_b,
    const float* __restrict__ fc4_w, const float* __restrict__ fc4_b,
    const float* __restrict__ sell_v_w, const float* __restrict__ sell_v_b,
    const float* __restrict__ sell_q_w, const float* __restrict__ sell_q_b,
    const float* __restrict__ buy_v_w, const float* __restrict__ buy_v_b,
    const float* __restrict__ buy_q_w, const float* __restrict__ buy_q_b,
    float* __restrict__ out) {

  __shared__ unsigned short A_lds[BROWS][APAD];  // bf16 bits: [r][k], k<64 = x_t, 64..319 = h
  __shared__ float feat[BROWS][258];             // [net_pnl(2) | h_fin(256)] fp32
  __shared__ float v_lds[BROWS][128];
  __shared__ float q_lds[BROWS][128];
  __shared__ float ispos_lds[BROWS];

  const int tid = threadIdx.x;
  const int w   = tid >> 6;       // wave 0..7
  const int l   = tid & 63;
  const int cl  = l & 15;         // column-in-tile / A-row
  const int kg  = l >> 4;         // 0..3
  const int rb  = blockIdx.x * BROWS;

  // ---- prologue: zero LDS A buffer, stage x_0 ----
  for (int i = tid; i < BROWS * APAD; i += 512)
    ((unsigned short*)A_lds)[i] = 0;
  __syncthreads();
  {
    const int r  = tid >> 5;
    const int f0 = (tid & 31) * 2;
    const float2 xv = *(const float2*)&history[((size_t)(rb + r) * T_STEPS + 0) * F_DIM + f0];
    unsigned int packed = (unsigned int)f2bf(xv.x) | ((unsigned int)f2bf(xv.y) << 16);
    *(unsigned int*)&A_lds[r][f0] = packed;
  }

  // ---- per-lane constants: this wave owns h-cols [(2w)*16 .. (2w+2)*16) ----
  float bias_r[2][4], wi_r[2], wf_r[2], wo_r[2];
  #pragma unroll
  for (int ct = 0; ct < 2; ++ct) {
    const int hc = (w * 2 + ct) * 16 + cl;
    wi_r[ct] = w_i[hc]; wf_r[ct] = w_f[hc]; wo_r[ct] = w_o[hc];
    #pragma unroll
    for (int g = 0; g < 4; ++g) bias_r[ct][g] = bias[g * 256 + hc];
  }

  float c_st[2][4];
  #pragma unroll
  for (int ct = 0; ct < 2; ++ct)
    #pragma unroll
    for (int q = 0; q < 4; ++q) c_st[ct][q] = 0.0f;

  __syncthreads();

  // ---- the scan ----
  for (int t = 0; t < T_STEPS; ++t) {
    // A fragments (shared across all column tiles of this wave)
    bf16x8 afrag[KT_TOTAL];
    #pragma unroll
    for (int kt = 0; kt < KT_TOTAL; ++kt)
      afrag[kt] = *(const bf16x8*)&A_lds[cl][kt * 32 + kg * 8];

    f32x4 acc[2][4];
    #pragma unroll
    for (int ct = 0; ct < 2; ++ct)
      #pragma unroll
      for (int g = 0; g < 4; ++g)
        acc[ct][g] = (f32x4){0.f, 0.f, 0.f, 0.f};

    #pragma unroll
    for (int kt = 0; kt < KT_TOTAL; ++kt) {
      #pragma unroll
      for (int ct = 0; ct < 2; ++ct) {
        #pragma unroll
        for (int g = 0; g < 4; ++g) {
          const int ntile = g * 16 + (w * 2 + ct);
          const bf16x8 b =
              *(const bf16x8*)(Wp + ((size_t)(ntile * KT_TOTAL + kt) * 64 + l) * 8);
          acc[ct][g] = __builtin_amdgcn_mfma_f32_16x16x32_bf16(afrag[kt], b, acc[ct][g], 0, 0, 0);
        }
      }
    }

    // gates + state update (z order: i, j, f, o)
    float h_val[2][4];
    #pragma unroll
    for (int ct = 0; ct < 2; ++ct) {
      #pragma unroll
      for (int q = 0; q < 4; ++q) {
        const float c_old = c_st[ct][q];
        const float ig = sigmoid_f(acc[ct][0][q] + bias_r[ct][0] + wi_r[ct] * c_old);
        const float fg = sigmoid_f(acc[ct][2][q] + bias_r[ct][2] + 1.0f + wf_r[ct] * c_old);
        const float jg = tanhf(acc[ct][1][q] + bias_r[ct][1]);
        const float c_new = fg * c_old + ig * jg;
        const float og = sigmoid_f(acc[ct][3][q] + bias_r[ct][3] + wo_r[ct] * c_new);
        const float hv = og * tanhf(c_new);
        c_st[ct][q] = c_new;
        h_val[ct][q] = hv;
      }
    }

    __syncthreads();  // everyone done reading A_lds for step t

    // write h (bf16) for next step; save fp32 h at the last step
    #pragma unroll
    for (int ct = 0; ct < 2; ++ct) {
      const int hc = (w * 2 + ct) * 16 + cl;
      #pragma unroll
      for (int q = 0; q < 4; ++q) {
        const int r = 4 * kg + q;
        A_lds[r][64 + hc] = f2bf(h_val[ct][q]);
        if (t == T_STEPS - 1) feat[r][2 + hc] = h_val[ct][q];
      }
    }
    // stage x_{t+1}
    if (t + 1 < T_STEPS) {
      const int r  = tid >> 5;
      const int f0 = (tid & 31) * 2;
      const float2 xv =
          *(const float2*)&history[((size_t)(rb + r) * T_STEPS + (t + 1)) * F_DIM + f0];
      unsigned int packed = (unsigned int)f2bf(xv.x) | ((unsigned int)f2bf(xv.y) << 16);
      *(unsigned int*)&A_lds[r][f0] = packed;
    }
    __syncthreads();
  }

  // ---- head network ----
  if (tid < BROWS) {
    feat[tid][0] = head[(rb + tid) * 3 + 1];
    feat[tid][1] = head[(rb + tid) * 3 + 2];
    ispos_lds[tid] = head[(rb + tid) * 3 + 0];
  }
  __syncthreads();

  #pragma unroll
  for (int p = 0; p < 4; ++p) {
    const int idx = p * 512 + tid;
    const int r = idx >> 7, hh = idx & 127;
    float s3 = fc3_b[hh], s4 = fc4_b[hh];
    for (int k = 0; k < 258; ++k) {
      const float fv = feat[r][k];
      s3 += fv * fc3_w[k * 128 + hh];
      s4 += fv * fc4_w[k * 128 + hh];
    }
    v_lds[r][hh] = fmaxf(s3, 0.0f);
    q_lds[r][hh] = fmaxf(s4, 0.0f);
  }
  __syncthreads();

  if (tid < BROWS) {
    const int r = tid;
    float pa0 = sell_q_b[0], pa1 = sell_q_b[1];
    float ea0 = buy_q_b[0],  ea1 = buy_q_b[1];
    float sv = sell_v_b[0], bv = buy_v_b[0];
    for (int hh = 0; hh < 128; ++hh) {
      const float qv = q_lds[r][hh], vv = v_lds[r][hh];
      pa0 += qv * sell_q_w[hh * 2 + 0];
      pa1 += qv * sell_q_w[hh * 2 + 1];
      ea0 += qv * buy_q_w[hh * 2 + 0];
      ea1 += qv * buy_q_w[hh * 2 + 1];
      sv += vv * sell_v_w[hh];
      bv += vv * buy_v_w[hh];
    }
    const float pm = 0.5f * (pa0 + pa1), em = 0.5f * (ea0 + ea1);
    const float pq0 = pa0 - pm + sv, pq1 = pa1 - pm + sv;
    const float eq0 = ea0 - em + bv, eq1 = ea1 - em + bv;
    const float ip = ispos_lds[r];
    const bool m0 = (ip != 0.0f);
    const bool m1 = ((1.0f - ip) != 0.0f);
    out[(size_t)(rb + r) * 2 + 0] = m0 ? pq0 : eq0;
    out[(size_t)(rb + r) * 2 + 1] = m1 ? pq1 : eq1;
  }
}

extern "C" void kernel_launch(void* const* d_in, const int* in_sizes, int n_in,
                              void* d_out, int out_size, void* d_ws, size_t ws_size,
                              hipStream_t stream) {
  (void)in_sizes; (void)n_in; (void)out_size; (void)ws_size;
  const float* history  = (const float*)d_in[0];
  const float* head     = (const float*)d_in[1];
  const float* Wk       = (const float*)d_in[2];
  const float* bias     = (const float*)d_in[3];
  const float* w_i      = (const float*)d_in[4];
  const float* w_f      = (const float*)d_in[5];
  const float* w_o      = (const float*)d_in[6];
  const float* fc3_w    = (const float*)d_in[7];
  const float* fc3_b    = (const float*)d_in[8];
  const float* fc4_w    = (const float*)d_in[9];
  const float* fc4_b    = (const float*)d_in[10];
  const float* sell_v_w = (const float*)d_in[11];
  const float* sell_v_b = (const float*)d_in[12];
  const float* sell_q_w = (const float*)d_in[13];
  const float* sell_q_b = (const float*)d_in[14];
  const float* buy_v_w  = (const float*)d_in[15];
  const float* buy_v_b  = (const float*)d_in[16];
  const float* buy_q_w  = (const float*)d_in[17];
  const float* buy_q_b  = (const float*)d_in[18];

  unsigned short* Wp = (unsigned short*)d_ws;  // 320*1024 bf16 = 640 KiB

  pack_w_kernel<<<NT_TOTAL * KT_TOTAL, 64, 0, stream>>>(Wk, Wp);
  qlstm_kernel<<<B_TOTAL / BROWS, 512, 0, stream>>>(
      history, head, bias, w_i, w_f, w_o, Wp,
      fc3_w, fc3_b, fc4_w, fc4_b,
      sell_v_w, sell_v_b, sell_q_w, sell_q_b,
      buy_v_w, buy_v_b, buy_q_w, buy_q_b,
      (float*)d_out);
}

// Round 2
// 1103.252 us; speedup vs baseline: 1.4947x; 1.4947x over previous
//
#include <hip/hip_runtime.h>
#include <stdint.h>

#define B_TOTAL 1024
#define T_STEPS 128
#define F_DIM   64
#define H_DIM   256
#define K_DIM   320   // F_DIM + H_DIM
#define BROWS   16
#define APAD    324   // 16 rows * 324 shorts; row stride 648B = 162 dw ≡ 2 mod 32 banks
#define NSLOTS  640   // 8 waves * 80 frags; slot = w*80 + kt*8 + ct*4 + g

typedef float f32x4 __attribute__((ext_vector_type(4)));
typedef short bf16x8 __attribute__((ext_vector_type(8)));

__device__ __forceinline__ unsigned short f2bf(float f) {
  unsigned int u = __float_as_uint(f);
  u += 0x7fffu + ((u >> 16) & 1u);
  return (unsigned short)(u >> 16);
}
__device__ __forceinline__ float bf2f(unsigned short b) {
  return __uint_as_float(((unsigned int)b) << 16);
}
__device__ __forceinline__ float sigmoid_f(float x) {
  return 1.0f / (1.0f + __expf(-x));
}
__device__ __forceinline__ float tanh_f(float x) {
  return 1.0f - 2.0f / (1.0f + __expf(2.0f * x));
}

// Pack kernel weights (320x1024 fp32 row-major) into bf16 MFMA-B fragments,
// wave-major: slot = w*80 + kt*8 + ct*4 + g; ntile = g*16 + w*2 + ct.
// Wp[(slot*64 + l)*8 + j] = W[kt*32 + 8*(l>>4) + j][ntile*16 + (l&15)]
__global__ __launch_bounds__(64) void pack_w_kernel(const float* __restrict__ W,
                                                    unsigned short* __restrict__ Wp) {
  const int slot = blockIdx.x;
  const int w  = slot / 80, r = slot % 80;
  const int kt = r >> 3, ct = (r >> 2) & 1, g = r & 3;
  const int ntile = g * 16 + w * 2 + ct;
  const int l   = threadIdx.x;
  const int col = ntile * 16 + (l & 15);
  const int k0  = kt * 32 + (l >> 4) * 8;
  unsigned short* dst = Wp + ((size_t)slot * 64 + l) * 8;
  #pragma unroll
  for (int j = 0; j < 8; ++j)
    dst[j] = f2bf(W[(size_t)(k0 + j) * 1024 + col]);
}

__global__ __launch_bounds__(512, 2) void qlstm_kernel(
    const float* __restrict__ history, const float* __restrict__ head,
    const float* __restrict__ bias,
    const float* __restrict__ w_i, const float* __restrict__ w_f, const float* __restrict__ w_o,
    const unsigned short* __restrict__ Wp,
    const float* __restrict__ fc3_w, const float* __restrict__ fc3_b,
    const float* __restrict__ fc4_w, const float* __restrict__ fc4_b,
    const float* __restrict__ sell_v_w, const float* __restrict__ sell_v_b,
    const float* __restrict__ sell_q_w, const float* __restrict__ sell_q_b,
    const float* __restrict__ buy_v_w, const float* __restrict__ buy_v_b,
    const float* __restrict__ buy_q_w, const float* __restrict__ buy_q_b,
    float* __restrict__ out) {

  __shared__ unsigned short A_lds[BROWS][APAD];   // [r][k] bf16: k<64 = x_t, 64..319 = h
  __shared__ unsigned short W_lds[128 * 512];     // 128 KiB: kt 4..5 fragments, slot s = w*16 + (kt-4)*8 + ct*4 + g

  const int tid = threadIdx.x;
  const int w   = tid >> 6;       // wave 0..7
  const int l   = tid & 63;
  const int cl  = l & 15;         // A-row / acc-col
  const int kg  = l >> 4;         // 0..3
  const int rb  = blockIdx.x * BROWS;

  const unsigned short* wp_wl = Wp + (size_t)(w * 80) * 512 + l * 8;  // this wave's frags, this lane
  const unsigned short* wl_l  = W_lds + (w * 16) * 512 + l * 8;

  // ---- preload LDS-resident weight fragments (kt 4,5 of each wave) ----
  for (int i = tid; i < 128 * 64; i += 512) {
    const int s = i >> 6, l2 = i & 63;
    const int fsrc = (s >> 4) * 80 + 32 + (s & 15);
    *(uint4*)&W_lds[((size_t)s * 64 + l2) * 8] =
        *(const uint4*)&Wp[((size_t)fsrc * 64 + l2) * 8];
  }

  // ---- register-resident weight fragments: kt 0..3 ----
  bf16x8 wreg[4][2][4];
  #pragma unroll
  for (int kt = 0; kt < 4; ++kt)
    #pragma unroll
    for (int ct = 0; ct < 2; ++ct)
      #pragma unroll
      for (int g = 0; g < 4; ++g)
        wreg[kt][ct][g] = *(const bf16x8*)(wp_wl + (kt * 8 + ct * 4 + g) * 512);

  // ---- zero A, stage x_0 ----
  for (int i = tid; i < BROWS * APAD; i += 512)
    ((unsigned short*)A_lds)[i] = 0;
  __syncthreads();
  {
    const int r  = tid >> 5;
    const int f0 = (tid & 31) * 2;
    const float2 xv = *(const float2*)&history[((size_t)(rb + r) * T_STEPS + 0) * F_DIM + f0];
    *(unsigned int*)&A_lds[r][f0] =
        (unsigned int)f2bf(xv.x) | ((unsigned int)f2bf(xv.y) << 16);
  }

  // ---- per-lane gate constants: wave owns h-cols (w*2+ct)*16 + cl ----
  float bias_r[2][4], wi_r[2], wf_r[2], wo_r[2];
  #pragma unroll
  for (int ct = 0; ct < 2; ++ct) {
    const int hc = (w * 2 + ct) * 16 + cl;
    wi_r[ct] = w_i[hc]; wf_r[ct] = w_f[hc]; wo_r[ct] = w_o[hc];
    #pragma unroll
    for (int g = 0; g < 4; ++g) bias_r[ct][g] = bias[g * 256 + hc];
  }

  float c_st[2][4];
  #pragma unroll
  for (int ct = 0; ct < 2; ++ct)
    #pragma unroll
    for (int q = 0; q < 4; ++q) c_st[ct][q] = 0.0f;

  __syncthreads();

  // ---- the scan ----
  for (int t = 0; t < T_STEPS; ++t) {
    f32x4 acc[2][4];
    #pragma unroll
    for (int ct = 0; ct < 2; ++ct)
      #pragma unroll
      for (int g = 0; g < 4; ++g)
        acc[ct][g] = (f32x4){0.f, 0.f, 0.f, 0.f};

    // issue streamed kt=6 batch now; consumed after ~48 MFMAs
    bf16x8 sbuf[2][4];
    #pragma unroll
    for (int ct = 0; ct < 2; ++ct)
      #pragma unroll
      for (int g = 0; g < 4; ++g)
        sbuf[ct][g] = *(const bf16x8*)(wp_wl + (6 * 8 + ct * 4 + g) * 512);

    // kt 0..3: register weights
    #pragma unroll
    for (int kt = 0; kt < 4; ++kt) {
      const bf16x8 af = *(const bf16x8*)&A_lds[cl][kt * 32 + kg * 8];
      #pragma unroll
      for (int ct = 0; ct < 2; ++ct)
        #pragma unroll
        for (int g = 0; g < 4; ++g)
          acc[ct][g] = __builtin_amdgcn_mfma_f32_16x16x32_bf16(af, wreg[kt][ct][g], acc[ct][g], 0, 0, 0);
    }

    // kt 4..5: LDS-resident weights
    #pragma unroll
    for (int kt = 4; kt < 6; ++kt) {
      const bf16x8 af = *(const bf16x8*)&A_lds[cl][kt * 32 + kg * 8];
      #pragma unroll
      for (int ct = 0; ct < 2; ++ct)
        #pragma unroll
        for (int g = 0; g < 4; ++g) {
          const bf16x8 b = *(const bf16x8*)(wl_l + ((kt - 4) * 8 + ct * 4 + g) * 512);
          acc[ct][g] = __builtin_amdgcn_mfma_f32_16x16x32_bf16(af, b, acc[ct][g], 0, 0, 0);
        }
    }

    // kt 6..9: streamed weights through sbuf; reissue slot right after consumption
    #pragma unroll
    for (int kt = 6; kt < 10; ++kt) {
      const bf16x8 af = *(const bf16x8*)&A_lds[cl][kt * 32 + kg * 8];
      #pragma unroll
      for (int ct = 0; ct < 2; ++ct)
        #pragma unroll
        for (int g = 0; g < 4; ++g) {
          acc[ct][g] = __builtin_amdgcn_mfma_f32_16x16x32_bf16(af, sbuf[ct][g], acc[ct][g], 0, 0, 0);
          if (kt < 9)
            sbuf[ct][g] = *(const bf16x8*)(wp_wl + ((kt + 1) * 8 + ct * 4 + g) * 512);
        }
    }

    // gates + state update (z order: i, j, f, o)
    float h_val[2][4];
    #pragma unroll
    for (int ct = 0; ct < 2; ++ct) {
      #pragma unroll
      for (int q = 0; q < 4; ++q) {
        const float c_old = c_st[ct][q];
        const float ig = sigmoid_f(acc[ct][0][q] + bias_r[ct][0] + wi_r[ct] * c_old);
        const float fg = sigmoid_f(acc[ct][2][q] + bias_r[ct][2] + 1.0f + wf_r[ct] * c_old);
        const float jg = tanh_f(acc[ct][1][q] + bias_r[ct][1]);
        const float c_new = fg * c_old + ig * jg;
        const float og = sigmoid_f(acc[ct][3][q] + bias_r[ct][3] + wo_r[ct] * c_new);
        c_st[ct][q] = c_new;
        h_val[ct][q] = og * tanh_f(c_new);
      }
    }

    __syncthreads();  // all A_lds reads for step t done

    #pragma unroll
    for (int ct = 0; ct < 2; ++ct) {
      const int hc = (w * 2 + ct) * 16 + cl;
      #pragma unroll
      for (int q = 0; q < 4; ++q)
        A_lds[4 * kg + q][64 + hc] = f2bf(h_val[ct][q]);
    }
    if (t + 1 < T_STEPS) {
      const int r  = tid >> 5;
      const int f0 = (tid & 31) * 2;
      const float2 xv =
          *(const float2*)&history[((size_t)(rb + r) * T_STEPS + (t + 1)) * F_DIM + f0];
      *(unsigned int*)&A_lds[r][f0] =
          (unsigned int)f2bf(xv.x) | ((unsigned int)f2bf(xv.y) << 16);
    }
    __syncthreads();
  }

  // ---- epilogue: overlay scratch onto W_lds (all weight reads are done) ----
  float* feat   = (float*)W_lds;            // [16][258]
  float* v_l    = feat + BROWS * 258;       // [16][128]
  float* q_l    = v_l + BROWS * 128;        // [16][128]
  float* ispos  = q_l + BROWS * 128;        // [16]

  for (int i = tid; i < BROWS * H_DIM; i += 512) {
    const int r = i >> 8, hc = i & 255;
    feat[r * 258 + 2 + hc] = bf2f(A_lds[r][64 + hc]);
  }
  if (tid < BROWS) {
    feat[tid * 258 + 0] = head[(rb + tid) * 3 + 1];
    feat[tid * 258 + 1] = head[(rb + tid) * 3 + 2];
    ispos[tid] = head[(rb + tid) * 3 + 0];
  }
  __syncthreads();

  #pragma unroll
  for (int p = 0; p < 4; ++p) {
    const int idx = p * 512 + tid;
    const int r = idx >> 7, hh = idx & 127;
    float s3 = fc3_b[hh], s4 = fc4_b[hh];
    for (int k = 0; k < 258; ++k) {
      const float fv = feat[r * 258 + k];
      s3 += fv * fc3_w[k * 128 + hh];
      s4 += fv * fc4_w[k * 128 + hh];
    }
    v_l[r * 128 + hh] = fmaxf(s3, 0.0f);
    q_l[r * 128 + hh] = fmaxf(s4, 0.0f);
  }
  __syncthreads();

  if (tid < BROWS) {
    const int r = tid;
    float pa0 = sell_q_b[0], pa1 = sell_q_b[1];
    float ea0 = buy_q_b[0],  ea1 = buy_q_b[1];
    float sv = sell_v_b[0], bv = buy_v_b[0];
    for (int hh = 0; hh < 128; ++hh) {
      const float qv = q_l[r * 128 + hh], vv = v_l[r * 128 + hh];
      pa0 += qv * sell_q_w[hh * 2 + 0];
      pa1 += qv * sell_q_w[hh * 2 + 1];
      ea0 += qv * buy_q_w[hh * 2 + 0];
      ea1 += qv * buy_q_w[hh * 2 + 1];
      sv += vv * sell_v_w[hh];
      bv += vv * buy_v_w[hh];
    }
    const float pm = 0.5f * (pa0 + pa1), em = 0.5f * (ea0 + ea1);
    const float pq0 = pa0 - pm + sv, pq1 = pa1 - pm + sv;
    const float eq0 = ea0 - em + bv, eq1 = ea1 - em + bv;
    const float ip = ispos[r];
    out[(size_t)(rb + r) * 2 + 0] = (ip != 0.0f) ? pq0 : eq0;
    out[(size_t)(rb + r) * 2 + 1] = ((1.0f - ip) != 0.0f) ? pq1 : eq1;
  }
}

extern "C" void kernel_launch(void* const* d_in, const int* in_sizes, int n_in,
                              void* d_out, int out_size, void* d_ws, size_t ws_size,
                              hipStream_t stream) {
  (void)in_sizes; (void)n_in; (void)out_size; (void)ws_size;
  const float* history  = (const float*)d_in[0];
  const float* head     = (const float*)d_in[1];
  const float* Wk       = (const float*)d_in[2];
  const float* bias     = (const float*)d_in[3];
  const float* w_i      = (const float*)d_in[4];
  const float* w_f      = (const float*)d_in[5];
  const float* w_o      = (const float*)d_in[6];
  const float* fc3_w    = (const float*)d_in[7];
  const float* fc3_b    = (const float*)d_in[8];
  const float* fc4_w    = (const float*)d_in[9];
  const float* fc4_b    = (const float*)d_in[10];
  const float* sell_v_w = (const float*)d_in[11];
  const float* sell_v_b = (const float*)d_in[12];
  const float* sell_q_w = (const float*)d_in[13];
  const float* sell_q_b = (const float*)d_in[14];
  const float* buy_v_w  = (const float*)d_in[15];
  const float* buy_v_b  = (const float*)d_in[16];
  const float* buy_q_w  = (const float*)d_in[17];
  const float* buy_q_b  = (const float*)d_in[18];

  unsigned short* Wp = (unsigned short*)d_ws;  // 640 slots * 1 KiB = 640 KiB

  pack_w_kernel<<<NSLOTS, 64, 0, stream>>>(Wk, Wp);
  qlstm_kernel<<<B_TOTAL / BROWS, 512, 0, stream>>>(
      history, head, bias, w_i, w_f, w_o, Wp,
      fc3_w, fc3_b, fc4_w, fc4_b,
      sell_v_w, sell_v_b, sell_q_w, sell_q_b,
      buy_v_w, buy_v_b, buy_q_w, buy_q_b,
      (float*)d_out);
}

// Round 3
// 789.752 us; speedup vs baseline: 2.0880x; 1.3970x over previous
//
#include <hip/hip_runtime.h>
#include <stdint.h>

#define B_TOTAL 1024
#define T_STEPS 128
#define F_DIM   64
#define H_DIM   256
#define BROWS   16
#define APAD    324   // row stride 648B -> bank offset 2 per row
#define NSLOTS  640   // 8 waves * 80 frags; slot = w*80 + kt*8 + ct*4 + g

typedef float f32x4 __attribute__((ext_vector_type(4)));
typedef short bf16x8 __attribute__((ext_vector_type(8)));

__device__ __forceinline__ unsigned short f2bf(float f) {
  unsigned int u = __float_as_uint(f);
  u += 0x7fffu + ((u >> 16) & 1u);
  return (unsigned short)(u >> 16);
}
__device__ __forceinline__ float bf2f(unsigned short b) {
  return __uint_as_float(((unsigned int)b) << 16);
}
__device__ __forceinline__ float sigmoid_f(float x) {
  return 1.0f / (1.0f + __expf(-x));
}
__device__ __forceinline__ float tanh_f(float x) {
  return 1.0f - 2.0f / (1.0f + __expf(2.0f * x));
}

// Pack kernel weights (320x1024 fp32 row-major) into bf16 MFMA-B fragments,
// wave-major: slot = w*80 + kt*8 + ct*4 + g; ntile = g*16 + w*2 + ct.
// Wp[(slot*64 + l)*8 + j] = W[kt*32 + 8*(l>>4) + j][ntile*16 + (l&15)]
__global__ __launch_bounds__(64) void pack_w_kernel(const float* __restrict__ W,
                                                    unsigned short* __restrict__ Wp) {
  const int slot = blockIdx.x;
  const int w  = slot / 80, r = slot % 80;
  const int kt = r >> 3, ct = (r >> 2) & 1, g = r & 3;
  const int ntile = g * 16 + w * 2 + ct;
  const int l   = threadIdx.x;
  const int col = ntile * 16 + (l & 15);
  const int k0  = kt * 32 + (l >> 4) * 8;
  unsigned short* dst = Wp + ((size_t)slot * 64 + l) * 8;
  #pragma unroll
  for (int j = 0; j < 8; ++j)
    dst[j] = f2bf(W[(size_t)(k0 + j) * 1024 + col]);
}

// Opaque pin: def becomes un-rematerializable -> value stays in VGPRs.
#define PIN(x) asm volatile("" : "+v"(x))

// Issue 4 streamed fragments (one (kt,ct) batch) via volatile asm loads:
// cannot be LICM-hoisted, cannot be sunk; vmcnt-countable.
#define ISSUE_BATCH(buf, kt, ct) do {                                        \
    const unsigned short* _p = wp_wl + ((kt) * 8 + (ct) * 4) * 512;          \
    asm volatile("global_load_dwordx4 %0, %4, off\n\t"                       \
                 "global_load_dwordx4 %1, %4, off offset:1024\n\t"           \
                 "global_load_dwordx4 %2, %4, off offset:2048\n\t"           \
                 "global_load_dwordx4 %3, %4, off offset:3072"               \
                 : "=&v"(buf[0]), "=&v"(buf[1]), "=&v"(buf[2]), "=&v"(buf[3])\
                 : "v"(_p));                                                 \
  } while (0)

// Counted wait + sched fence (rule #18), then 4 MFMAs into acc[ct].
#define CONSUME(buf, ct, N) do {                                             \
    asm volatile("s_waitcnt vmcnt(" #N ")" ::: "memory");                    \
    __builtin_amdgcn_sched_barrier(0);                                       \
    acc[ct][0] = __builtin_amdgcn_mfma_f32_16x16x32_bf16(af, buf[0], acc[ct][0], 0, 0, 0); \
    acc[ct][1] = __builtin_amdgcn_mfma_f32_16x16x32_bf16(af, buf[1], acc[ct][1], 0, 0, 0); \
    acc[ct][2] = __builtin_amdgcn_mfma_f32_16x16x32_bf16(af, buf[2], acc[ct][2], 0, 0, 0); \
    acc[ct][3] = __builtin_amdgcn_mfma_f32_16x16x32_bf16(af, buf[3], acc[ct][3], 0, 0, 0); \
  } while (0)

#define LD_A(kt) (*(const bf16x8*)&A_lds[cl][(kt) * 32 + kg * 8])

__global__ __launch_bounds__(512, 1) void qlstm_kernel(
    const float* __restrict__ history, const float* __restrict__ head,
    const float* __restrict__ bias,
    const float* __restrict__ w_i, const float* __restrict__ w_f, const float* __restrict__ w_o,
    const unsigned short* __restrict__ Wp,
    const float* __restrict__ fc3_w, const float* __restrict__ fc3_b,
    const float* __restrict__ fc4_w, const float* __restrict__ fc4_b,
    const float* __restrict__ sell_v_w, const float* __restrict__ sell_v_b,
    const float* __restrict__ sell_q_w, const float* __restrict__ sell_q_b,
    const float* __restrict__ buy_v_w, const float* __restrict__ buy_v_b,
    const float* __restrict__ buy_q_w, const float* __restrict__ buy_q_b,
    float* __restrict__ out) {

  __shared__ unsigned short A_lds[BROWS][APAD];  // bf16 bits: [r][k], k<64 = x_t, 64..319 = h
  __shared__ float feat[BROWS][258];
  __shared__ float v_lds[BROWS][128];
  __shared__ float q_lds[BROWS][128];
  __shared__ float ispos_lds[BROWS];

  const int tid = threadIdx.x;
  const int w   = tid >> 6;       // wave 0..7
  const int l   = tid & 63;
  const int cl  = l & 15;         // A-row / acc-col
  const int kg  = l >> 4;         // 0..3
  const int rb  = blockIdx.x * BROWS;

  const unsigned short* wp_wl = Wp + (size_t)(w * 80) * 512 + l * 8;

  // ---- register-resident tier: kt 0..2 (24 frags = 96 VGPRs), pinned ----
  bf16x8 wreg[3][2][4];
  #pragma unroll
  for (int kt = 0; kt < 3; ++kt)
    #pragma unroll
    for (int ct = 0; ct < 2; ++ct)
      #pragma unroll
      for (int g = 0; g < 4; ++g) {
        wreg[kt][ct][g] = *(const bf16x8*)(wp_wl + (kt * 8 + ct * 4 + g) * 512);
        PIN(wreg[kt][ct][g]);
      }

  // ---- zero A, stage x_0 ----
  for (int i = tid; i < BROWS * APAD; i += 512)
    ((unsigned short*)A_lds)[i] = 0;
  __syncthreads();
  {
    const int r  = tid >> 5;
    const int f0 = (tid & 31) * 2;
    const float2 xv = *(const float2*)&history[((size_t)(rb + r) * T_STEPS + 0) * F_DIM + f0];
    *(unsigned int*)&A_lds[r][f0] =
        (unsigned int)f2bf(xv.x) | ((unsigned int)f2bf(xv.y) << 16);
  }

  // ---- per-lane gate constants: wave owns h-cols (w*2+ct)*16 + cl ----
  float bias_r[2][4], wi_r[2], wf_r[2], wo_r[2];
  #pragma unroll
  for (int ct = 0; ct < 2; ++ct) {
    const int hc = (w * 2 + ct) * 16 + cl;
    wi_r[ct] = w_i[hc]; wf_r[ct] = w_f[hc]; wo_r[ct] = w_o[hc];
    #pragma unroll
    for (int g = 0; g < 4; ++g) bias_r[ct][g] = bias[g * 256 + hc];
  }

  float c_st[2][4];
  #pragma unroll
  for (int ct = 0; ct < 2; ++ct)
    #pragma unroll
    for (int q = 0; q < 4; ++q) c_st[ct][q] = 0.0f;

  __syncthreads();

  // ---- the scan ----
  for (int t = 0; t < T_STEPS; ++t) {
    f32x4 acc[2][4];
    #pragma unroll
    for (int ct = 0; ct < 2; ++ct)
      #pragma unroll
      for (int g = 0; g < 4; ++g)
        acc[ct][g] = (f32x4){0.f, 0.f, 0.f, 0.f};

    // next x_t prefetch: issued FIRST (oldest in vmcnt queue; any counted
    // wait below that drains to <=8 outstanding retires it first)
    float2 xv;
    const bool havex = (t + 1 < T_STEPS);
    if (havex) {
      const float* xp =
          &history[((size_t)(rb + (tid >> 5)) * T_STEPS + (t + 1)) * F_DIM + (tid & 31) * 2];
      asm volatile("global_load_dwordx2 %0, %1, off" : "=&v"(xv) : "v"(xp));
    }

    // stream pipeline: 14 batches (kt 3..9 x ct 0,1), 3 in flight
    bf16x8 sA[4], sB[4], sC[4];
    ISSUE_BATCH(sA, 3, 0);
    ISSUE_BATCH(sB, 3, 1);
    ISSUE_BATCH(sC, 4, 0);

    // register tier: kt 0..2 (covers L2 latency of the first batches)
    #pragma unroll
    for (int kt = 0; kt < 3; ++kt) {
      const bf16x8 afr = LD_A(kt);
      #pragma unroll
      for (int ct = 0; ct < 2; ++ct)
        #pragma unroll
        for (int g = 0; g < 4; ++g)
          acc[ct][g] =
              __builtin_amdgcn_mfma_f32_16x16x32_bf16(afr, wreg[kt][ct][g], acc[ct][g], 0, 0, 0);
    }

    bf16x8 af;
    af = LD_A(3);
    CONSUME(sA, 0, 8); ISSUE_BATCH(sA, 4, 1);
    CONSUME(sB, 1, 8); ISSUE_BATCH(sB, 5, 0);
    af = LD_A(4);
    CONSUME(sC, 0, 8); ISSUE_BATCH(sC, 5, 1);
    CONSUME(sA, 1, 8); ISSUE_BATCH(sA, 6, 0);
    af = LD_A(5);
    CONSUME(sB, 0, 8); ISSUE_BATCH(sB, 6, 1);
    CONSUME(sC, 1, 8); ISSUE_BATCH(sC, 7, 0);
    af = LD_A(6);
    CONSUME(sA, 0, 8); ISSUE_BATCH(sA, 7, 1);
    CONSUME(sB, 1, 8); ISSUE_BATCH(sB, 8, 0);
    af = LD_A(7);
    CONSUME(sC, 0, 8); ISSUE_BATCH(sC, 8, 1);
    CONSUME(sA, 1, 8); ISSUE_BATCH(sA, 9, 0);
    af = LD_A(8);
    CONSUME(sB, 0, 8); ISSUE_BATCH(sB, 9, 1);
    CONSUME(sC, 1, 8);
    af = LD_A(9);
    CONSUME(sA, 0, 4);
    CONSUME(sB, 1, 0);

    // gates + state update (z order: i, j, f, o)
    float h_val[2][4];
    #pragma unroll
    for (int ct = 0; ct < 2; ++ct) {
      #pragma unroll
      for (int q = 0; q < 4; ++q) {
        const float c_old = c_st[ct][q];
        const float ig = sigmoid_f(acc[ct][0][q] + bias_r[ct][0] + wi_r[ct] * c_old);
        const float fg = sigmoid_f(acc[ct][2][q] + bias_r[ct][2] + 1.0f + wf_r[ct] * c_old);
        const float jg = tanh_f(acc[ct][1][q] + bias_r[ct][1]);
        const float c_new = fg * c_old + ig * jg;
        const float og = sigmoid_f(acc[ct][3][q] + bias_r[ct][3] + wo_r[ct] * c_new);
        c_st[ct][q] = c_new;
        h_val[ct][q] = og * tanh_f(c_new);
      }
    }

    __syncthreads();  // all A_lds reads for step t done

    #pragma unroll
    for (int ct = 0; ct < 2; ++ct) {
      const int hc = (w * 2 + ct) * 16 + cl;
      #pragma unroll
      for (int q = 0; q < 4; ++q)
        A_lds[4 * kg + q][64 + hc] = f2bf(h_val[ct][q]);
    }
    if (havex) {
      const int r  = tid >> 5;
      const int f0 = (tid & 31) * 2;
      *(unsigned int*)&A_lds[r][f0] =
          (unsigned int)f2bf(xv.x) | ((unsigned int)f2bf(xv.y) << 16);
    }
    __syncthreads();
  }

  // ---- epilogue ----
  for (int i = tid; i < BROWS * H_DIM; i += 512) {
    const int r = i >> 8, hc = i & 255;
    feat[r][2 + hc] = bf2f(A_lds[r][64 + hc]);
  }
  if (tid < BROWS) {
    feat[tid][0] = head[(rb + tid) * 3 + 1];
    feat[tid][1] = head[(rb + tid) * 3 + 2];
    ispos_lds[tid] = head[(rb + tid) * 3 + 0];
  }
  __syncthreads();

  #pragma unroll
  for (int p = 0; p < 4; ++p) {
    const int idx = p * 512 + tid;
    const int r = idx >> 7, hh = idx & 127;
    float s3 = fc3_b[hh], s4 = fc4_b[hh];
    for (int k = 0; k < 258; ++k) {
      const float fv = feat[r][k];
      s3 += fv * fc3_w[k * 128 + hh];
      s4 += fv * fc4_w[k * 128 + hh];
    }
    v_lds[r][hh] = fmaxf(s3, 0.0f);
    q_lds[r][hh] = fmaxf(s4, 0.0f);
  }
  __syncthreads();

  if (tid < BROWS) {
    const int r = tid;
    float pa0 = sell_q_b[0], pa1 = sell_q_b[1];
    float ea0 = buy_q_b[0],  ea1 = buy_q_b[1];
    float sv = sell_v_b[0], bv = buy_v_b[0];
    for (int hh = 0; hh < 128; ++hh) {
      const float qv = q_lds[r][hh], vv = v_lds[r][hh];
      pa0 += qv * sell_q_w[hh * 2 + 0];
      pa1 += qv * sell_q_w[hh * 2 + 1];
      ea0 += qv * buy_q_w[hh * 2 + 0];
      ea1 += qv * buy_q_w[hh * 2 + 1];
      sv += vv * sell_v_w[hh];
      bv += vv * buy_v_w[hh];
    }
    const float pm = 0.5f * (pa0 + pa1), em = 0.5f * (ea0 + ea1);
    const float pq0 = pa0 - pm + sv, pq1 = pa1 - pm + sv;
    const float eq0 = ea0 - em + bv, eq1 = ea1 - em + bv;
    const float ip = ispos_lds[r];
    out[(size_t)(rb + r) * 2 + 0] = (ip != 0.0f) ? pq0 : eq0;
    out[(size_t)(rb + r) * 2 + 1] = ((1.0f - ip) != 0.0f) ? pq1 : eq1;
  }
}

extern "C" void kernel_launch(void* const* d_in, const int* in_sizes, int n_in,
                              void* d_out, int out_size, void* d_ws, size_t ws_size,
                              hipStream_t stream) {
  (void)in_sizes; (void)n_in; (void)out_size; (void)ws_size;
  const float* history  = (const float*)d_in[0];
  const float* head     = (const float*)d_in[1];
  const float* Wk       = (const float*)d_in[2];
  const float* bias     = (const float*)d_in[3];
  const float* w_i      = (const float*)d_in[4];
  const float* w_f      = (const float*)d_in[5];
  const float* w_o      = (const float*)d_in[6];
  const float* fc3_w    = (const float*)d_in[7];
  const float* fc3_b    = (const float*)d_in[8];
  const float* fc4_w    = (const float*)d_in[9];
  const float* fc4_b    = (const float*)d_in[10];
  const float* sell_v_w = (const float*)d_in[11];
  const float* sell_v_b = (const float*)d_in[12];
  const float* sell_q_w = (const float*)d_in[13];
  const float* sell_q_b = (const float*)d_in[14];
  const float* buy_v_w  = (const float*)d_in[15];
  const float* buy_v_b  = (const float*)d_in[16];
  const float* buy_q_w  = (const float*)d_in[17];
  const float* buy_q_b  = (const float*)d_in[18];

  unsigned short* Wp = (unsigned short*)d_ws;  // 640 slots * 1 KiB = 640 KiB

  pack_w_kernel<<<NSLOTS, 64, 0, stream>>>(Wk, Wp);
  qlstm_kernel<<<B_TOTAL / BROWS, 512, 0, stream>>>(
      history, head, bias, w_i, w_f, w_o, Wp,
      fc3_w, fc3_b, fc4_w, fc4_b,
      sell_v_w, sell_v_b, sell_q_w, sell_q_b,
      buy_v_w, buy_v_b, buy_q_w, buy_q_b,
      (float*)d_out);
}

// Round 7
// 681.752 us; speedup vs baseline: 2.4188x; 1.1584x over previous
//
#include <hip/hip_runtime.h>
#include <stdint.h>

#define B_TOTAL 1024
#define T_STEPS 128
#define F_DIM   64
#define H_DIM   256
#define BROWS   16
#define APAD    324   // row stride 648B
#define NSLOTS  640   // 8 waves * 80 frags; slot = w*80 + kt*8 + ct*4 + g

typedef float f32x4 __attribute__((ext_vector_type(4)));
typedef short bf16x8 __attribute__((ext_vector_type(8)));

__device__ __forceinline__ unsigned short f2bf(float f) {
  unsigned int u = __float_as_uint(f);
  u += 0x7fffu + ((u >> 16) & 1u);
  return (unsigned short)(u >> 16);
}
__device__ __forceinline__ float bf2f(unsigned short b) {
  return __uint_as_float(((unsigned int)b) << 16);
}
__device__ __forceinline__ float sigmoid_f(float x) {
  return 1.0f / (1.0f + __expf(-x));
}
__device__ __forceinline__ float tanh_f(float x) {
  return 1.0f - 2.0f / (1.0f + __expf(2.0f * x));
}

// Pack kernel weights (320x1024 fp32 row-major) into bf16 MFMA-B fragments,
// wave-major: slot = w*80 + kt*8 + ct*4 + g; ntile = g*16 + w*2 + ct.
__global__ __launch_bounds__(64) void pack_w_kernel(const float* __restrict__ W,
                                                    unsigned short* __restrict__ Wp) {
  const int slot = blockIdx.x;
  const int w  = slot / 80, r = slot % 80;
  const int kt = r >> 3, ct = (r >> 2) & 1, g = r & 3;
  const int ntile = g * 16 + w * 2 + ct;
  const int l   = threadIdx.x;
  const int col = ntile * 16 + (l & 15);
  const int k0  = kt * 32 + (l >> 4) * 8;
  unsigned short* dst = Wp + ((size_t)slot * 64 + l) * 8;
  #pragma unroll
  for (int j = 0; j < 8; ++j)
    dst[j] = f2bf(W[(size_t)(k0 + j) * 1024 + col]);
}

// Opaque pin: un-rematerializable def -> stays in unified VGPR/AGPR file.
#define PIN(x) asm volatile("" : "+v"(x))

// Issue 4 streamed fragments of (kt,ct). Round-3-proven addressing:
// Wp is shorts, one frag slot = 512 shorts; f = kt*8 + ct*4 + g.
// Buffers live ONLY within one loop iteration (no loop-carried async regs).
#define ISSUE_BATCH(buf, kt, ct) do {                                        \
    const unsigned short* _p = wp_wl + ((kt) * 8 + (ct) * 4) * 512;          \
    asm volatile("global_load_dwordx4 %0, %4, off\n\t"                       \
                 "global_load_dwordx4 %1, %4, off offset:1024\n\t"           \
                 "global_load_dwordx4 %2, %4, off offset:2048\n\t"           \
                 "global_load_dwordx4 %3, %4, off offset:3072"               \
                 : "=&v"(buf[0]), "=&v"(buf[1]), "=&v"(buf[2]), "=&v"(buf[3])\
                 : "v"(_p));                                                 \
  } while (0)

// Counted wait + sched fences (rule #18), 4 MFMAs into acc[ct].
#define CONSUME_S(buf, ct, afv, N) do {                                      \
    asm volatile("s_waitcnt vmcnt(" #N ")" ::: "memory");                    \
    __builtin_amdgcn_sched_barrier(0);                                       \
    acc[ct][0] = __builtin_amdgcn_mfma_f32_16x16x32_bf16(afv, buf[0], acc[ct][0], 0, 0, 0); \
    acc[ct][1] = __builtin_amdgcn_mfma_f32_16x16x32_bf16(afv, buf[1], acc[ct][1], 0, 0, 0); \
    acc[ct][2] = __builtin_amdgcn_mfma_f32_16x16x32_bf16(afv, buf[2], acc[ct][2], 0, 0, 0); \
    acc[ct][3] = __builtin_amdgcn_mfma_f32_16x16x32_bf16(afv, buf[3], acc[ct][3], 0, 0, 0); \
    __builtin_amdgcn_sched_barrier(0);                                       \
  } while (0)

#define LD_A(kt) (*(const bf16x8*)&A_lds[cl][(kt) * 32 + kg * 8])

__global__ __launch_bounds__(512, 1) void qlstm_kernel(
    const float* __restrict__ history, const float* __restrict__ head,
    const float* __restrict__ bias,
    const float* __restrict__ w_i, const float* __restrict__ w_f, const float* __restrict__ w_o,
    const unsigned short* __restrict__ Wp,
    const float* __restrict__ fc3_w, const float* __restrict__ fc3_b,
    const float* __restrict__ fc4_w, const float* __restrict__ fc4_b,
    const float* __restrict__ sell_v_w, const float* __restrict__ sell_v_b,
    const float* __restrict__ sell_q_w, const float* __restrict__ sell_q_b,
    const float* __restrict__ buy_v_w, const float* __restrict__ buy_v_b,
    const float* __restrict__ buy_q_w, const float* __restrict__ buy_q_b,
    float* __restrict__ out) {

  __shared__ unsigned short A_lds[BROWS][APAD];   // bf16: [r][k], k<64 = x_t, 64..319 = h
  __shared__ unsigned short W_lds[128 * 512];     // 128 KiB: kt4,5; slot s = w*16 + (kt-4)*8 + ct*4 + g

  const int tid = threadIdx.x;
  const int w   = tid >> 6;       // wave 0..7
  const int l   = tid & 63;
  const int cl  = l & 15;         // A-row / acc-col
  const int kg  = l >> 4;         // 0..3
  const int rb  = blockIdx.x * BROWS;

  const unsigned short* wp_wl = Wp + (size_t)(w * 80) * 512 + l * 8;
  const unsigned short* wl_l  = W_lds + (w * 16) * 512 + l * 8;

  // ---- preload LDS weight tier: frags f=32..47 (kt4,5) per wave ----
  for (int i = tid; i < 128 * 64; i += 512) {
    const int s = i >> 6, l2 = i & 63;
    const int fsrc = (s >> 4) * 80 + 32 + (s & 15);   // = w*80 + kt*8+ct*4+g, kt in {4,5}
    *(uint4*)&W_lds[((size_t)s * 64 + l2) * 8] =
        *(const uint4*)&Wp[((size_t)fsrc * 64 + l2) * 8];
  }

  // ---- register tier: kt 0..2 (24 frags = 96 regs), pinned ----
  bf16x8 wreg[3][2][4];
  #pragma unroll
  for (int kt = 0; kt < 3; ++kt)
    #pragma unroll
    for (int ct = 0; ct < 2; ++ct)
      #pragma unroll
      for (int g = 0; g < 4; ++g) {
        wreg[kt][ct][g] = *(const bf16x8*)(wp_wl + (kt * 8 + ct * 4 + g) * 512);
        PIN(wreg[kt][ct][g]);
      }

  // ---- zero A, stage x_0 ----
  for (int i = tid; i < BROWS * APAD; i += 512)
    ((unsigned short*)A_lds)[i] = 0;
  __syncthreads();
  {
    const int r  = tid >> 5;
    const int f0 = (tid & 31) * 2;
    const float2 xv0 = *(const float2*)&history[((size_t)(rb + r) * T_STEPS + 0) * F_DIM + f0];
    *(unsigned int*)&A_lds[r][f0] =
        (unsigned int)f2bf(xv0.x) | ((unsigned int)f2bf(xv0.y) << 16);
  }

  // ---- per-lane gate constants ----
  float bias_r[2][4], wi_r[2], wf_r[2], wo_r[2];
  #pragma unroll
  for (int ct = 0; ct < 2; ++ct) {
    const int hc = (w * 2 + ct) * 16 + cl;
    wi_r[ct] = w_i[hc]; wf_r[ct] = w_f[hc]; wo_r[ct] = w_o[hc];
    #pragma unroll
    for (int g = 0; g < 4; ++g) bias_r[ct][g] = bias[g * 256 + hc];
  }

  float c_st[2][4];
  #pragma unroll
  for (int ct = 0; ct < 2; ++ct)
    #pragma unroll
    for (int q = 0; q < 4; ++q) c_st[ct][q] = 0.0f;

  __syncthreads();

  // ---- the scan. All stream state is iteration-local (round-3 structure). ----
  for (int t = 0; t < T_STEPS; ++t) {
    // x prefetch for t+1: issued FIRST -> oldest in vmcnt queue, retired by
    // the first vmcnt(8) below.
    float2 xv;
    const bool havex = (t + 1 < T_STEPS);
    if (havex) {
      const float* xp =
          &history[((size_t)(rb + (tid >> 5)) * T_STEPS + (t + 1)) * F_DIM + (tid & 31) * 2];
      asm volatile("global_load_dwordx2 %0, %1, off" : "=&v"(xv) : "v"(xp));
    }

    f32x4 acc[2][4];
    #pragma unroll
    for (int ct = 0; ct < 2; ++ct)
      #pragma unroll
      for (int g = 0; g < 4; ++g)
        acc[ct][g] = (f32x4){0.f, 0.f, 0.f, 0.f};

    // stream tier = kt3 + kt6..9 (10 batches), triple-buffered, in-iteration
    bf16x8 sA[4], sB[4], sC[4];
    ISSUE_BATCH(sA, 3, 0);
    ISSUE_BATCH(sB, 3, 1);
    ISSUE_BATCH(sC, 6, 0);

    // reg tier kt0..2 (covers L2 latency of the first batches)
    #pragma unroll
    for (int kt = 0; kt < 3; ++kt) {
      const bf16x8 afr = LD_A(kt);
      #pragma unroll
      for (int ct = 0; ct < 2; ++ct)
        #pragma unroll
        for (int g = 0; g < 4; ++g)
          acc[ct][g] =
              __builtin_amdgcn_mfma_f32_16x16x32_bf16(afr, wreg[kt][ct][g], acc[ct][g], 0, 0, 0);
    }

    // LDS tier kt4..5 (LDS pipe, parallel to the stream)
    #pragma unroll
    for (int kt = 4; kt < 6; ++kt) {
      const bf16x8 afr = LD_A(kt);
      #pragma unroll
      for (int ct = 0; ct < 2; ++ct)
        #pragma unroll
        for (int g = 0; g < 4; ++g) {
          const bf16x8 b = *(const bf16x8*)(wl_l + ((kt - 4) * 8 + ct * 4 + g) * 512);
          acc[ct][g] = __builtin_amdgcn_mfma_f32_16x16x32_bf16(afr, b, acc[ct][g], 0, 0, 0);
        }
    }

    // ladder: rotation A,B,C; each ISSUE refills the just-consumed buffer
    bf16x8 af;
    af = LD_A(3);
    CONSUME_S(sA, 0, af, 8); ISSUE_BATCH(sA, 6, 1);
    CONSUME_S(sB, 1, af, 8); ISSUE_BATCH(sB, 7, 0);
    af = LD_A(6);
    CONSUME_S(sC, 0, af, 8); ISSUE_BATCH(sC, 7, 1);
    CONSUME_S(sA, 1, af, 8); ISSUE_BATCH(sA, 8, 0);
    af = LD_A(7);
    CONSUME_S(sB, 0, af, 8); ISSUE_BATCH(sB, 8, 1);
    CONSUME_S(sC, 1, af, 8); ISSUE_BATCH(sC, 9, 0);
    af = LD_A(8);
    CONSUME_S(sA, 0, af, 8); ISSUE_BATCH(sA, 9, 1);
    CONSUME_S(sB, 1, af, 8);
    af = LD_A(9);
    CONSUME_S(sC, 0, af, 4);
    CONSUME_S(sA, 1, af, 0);
    // queue now EMPTY: nothing outstanding crosses the barrier.

    // gates + state update (z order: i, j, f, o)
    float h_val[2][4];
    #pragma unroll
    for (int ct = 0; ct < 2; ++ct) {
      #pragma unroll
      for (int q = 0; q < 4; ++q) {
        const float c_old = c_st[ct][q];
        const float ig = sigmoid_f(acc[ct][0][q] + bias_r[ct][0] + wi_r[ct] * c_old);
        const float fg = sigmoid_f(acc[ct][2][q] + bias_r[ct][2] + 1.0f + wf_r[ct] * c_old);
        const float jg = tanh_f(acc[ct][1][q] + bias_r[ct][1]);
        const float c_new = fg * c_old + ig * jg;
        const float og = sigmoid_f(acc[ct][3][q] + bias_r[ct][3] + wo_r[ct] * c_new);
        c_st[ct][q] = c_new;
        h_val[ct][q] = og * tanh_f(c_new);
      }
    }

    __syncthreads();  // all A_lds reads for step t done

    #pragma unroll
    for (int ct = 0; ct < 2; ++ct) {
      const int hc = (w * 2 + ct) * 16 + cl;
      #pragma unroll
      for (int q = 0; q < 4; ++q)
        A_lds[4 * kg + q][64 + hc] = f2bf(h_val[ct][q]);
    }
    if (havex) {
      const int r  = tid >> 5;
      const int f0 = (tid & 31) * 2;
      *(unsigned int*)&A_lds[r][f0] =
          (unsigned int)f2bf(xv.x) | ((unsigned int)f2bf(xv.y) << 16);
    }
    __syncthreads();
  }

  // safety drain before LDS overlay reuse
  asm volatile("s_waitcnt vmcnt(0)" ::: "memory");
  __builtin_amdgcn_sched_barrier(0);
  __syncthreads();

  // ---- epilogue: overlay scratch onto W_lds (all weight reads done) ----
  float* feat  = (float*)W_lds;            // [16][258]
  float* v_l   = feat + BROWS * 258;       // [16][128]
  float* q_l   = v_l + BROWS * 128;        // [16][128]
  float* ispos = q_l + BROWS * 128;        // [16]

  for (int i = tid; i < BROWS * H_DIM; i += 512) {
    const int r = i >> 8, hc = i & 255;
    feat[r * 258 + 2 + hc] = bf2f(A_lds[r][64 + hc]);
  }
  if (tid < BROWS) {
    feat[tid * 258 + 0] = head[(rb + tid) * 3 + 1];
    feat[tid * 258 + 1] = head[(rb + tid) * 3 + 2];
    ispos[tid] = head[(rb + tid) * 3 + 0];
  }
  __syncthreads();

  #pragma unroll
  for (int p = 0; p < 4; ++p) {
    const int idx = p * 512 + tid;
    const int r = idx >> 7, hh = idx & 127;
    float s3 = fc3_b[hh], s4 = fc4_b[hh];
    for (int k = 0; k < 258; ++k) {
      const float fv = feat[r * 258 + k];
      s3 += fv * fc3_w[k * 128 + hh];
      s4 += fv * fc4_w[k * 128 + hh];
    }
    v_l[r * 128 + hh] = fmaxf(s3, 0.0f);
    q_l[r * 128 + hh] = fmaxf(s4, 0.0f);
  }
  __syncthreads();

  if (tid < BROWS) {
    const int r = tid;
    float pa0 = sell_q_b[0], pa1 = sell_q_b[1];
    float ea0 = buy_q_b[0],  ea1 = buy_q_b[1];
    float sv = sell_v_b[0], bv = buy_v_b[0];
    for (int hh = 0; hh < 128; ++hh) {
      const float qv = q_l[r * 128 + hh], vv = v_l[r * 128 + hh];
      pa0 += qv * sell_q_w[hh * 2 + 0];
      pa1 += qv * sell_q_w[hh * 2 + 1];
      ea0 += qv * buy_q_w[hh * 2 + 0];
      ea1 += qv * buy_q_w[hh * 2 + 1];
      sv += vv * sell_v_w[hh];
      bv += vv * buy_v_w[hh];
    }
    const float pm = 0.5f * (pa0 + pa1), em = 0.5f * (ea0 + ea1);
    const float pq0 = pa0 - pm + sv, pq1 = pa1 - pm + sv;
    const float eq0 = ea0 - em + bv, eq1 = ea1 - em + bv;
    const float ip = ispos[r];
    out[(size_t)(rb + r) * 2 + 0] = (ip != 0.0f) ? pq0 : eq0;
    out[(size_t)(rb + r) * 2 + 1] = ((1.0f - ip) != 0.0f) ? pq1 : eq1;
  }
}

extern "C" void kernel_launch(void* const* d_in, const int* in_sizes, int n_in,
                              void* d_out, int out_size, void* d_ws, size_t ws_size,
                              hipStream_t stream) {
  (void)in_sizes; (void)n_in; (void)out_size; (void)ws_size;
  const float* history  = (const float*)d_in[0];
  const float* head     = (const float*)d_in[1];
  const float* Wk       = (const float*)d_in[2];
  const float* bias     = (const float*)d_in[3];
  const float* w_i      = (const float*)d_in[4];
  const float* w_f      = (const float*)d_in[5];
  const float* w_o      = (const float*)d_in[6];
  const float* fc3_w    = (const float*)d_in[7];
  const float* fc3_b    = (const float*)d_in[8];
  const float* fc4_w    = (const float*)d_in[9];
  const float* fc4_b    = (const float*)d_in[10];
  const float* sell_v_w = (const float*)d_in[11];
  const float* sell_v_b = (const float*)d_in[12];
  const float* sell_q_w = (const float*)d_in[13];
  const float* sell_q_b = (const float*)d_in[14];
  const float* buy_v_w  = (const float*)d_in[15];
  const float* buy_v_b  = (const float*)d_in[16];
  const float* buy_q_w  = (const float*)d_in[17];
  const float* buy_q_b  = (const float*)d_in[18];

  unsigned short* Wp = (unsigned short*)d_ws;  // 640 slots * 1 KiB = 640 KiB

  pack_w_kernel<<<NSLOTS, 64, 0, stream>>>(Wk, Wp);
  qlstm_kernel<<<B_TOTAL / BROWS, 512, 0, stream>>>(
      history, head, bias, w_i, w_f, w_o, Wp,
      fc3_w, fc3_b, fc4_w, fc4_b,
      sell_v_w, sell_v_b, sell_q_w, sell_q_b,
      buy_v_w, buy_v_b, buy_q_w, buy_q_b,
      (float*)d_out);
}